// Round 2
// baseline (686.728 us; speedup 1.0000x reference)
//
#include <hip/hip_runtime.h>
#include <float.h>
#include <math.h>

#define TOKENS 16384
#define HIDDEN 2048
#define NEXP 128
#define TOPK 8
#define NCAND 12

typedef float f32x4 __attribute__((ext_vector_type(4)));
typedef short bf16x8 __attribute__((ext_vector_type(8)));

__device__ __forceinline__ unsigned short f2bf(float f) {
    unsigned u = __float_as_uint(f);
    u = (u + 0x7fffu + ((u >> 16) & 1u)) >> 16;   // RNE
    return (unsigned short)u;
}

// ---------------------------------------------------------------------------
// Kernel 1: bf16 MFMA GEMM. logits[t][e] = sum_k X[t][k] * W[e][k]
// 512 blocks x 256 threads. Block tile: 32 tokens x 128 experts, BK=32.
// Waves: wm = wid&1 (16-token half), wn = wid>>1 (64-expert half, 4 n-tiles).
// LDS in fragment order: lane reads 16B at (tile*64+lane)*16 -> uniform banks.
// A/B frag layout (guide §3): row = lane&15, k = (lane>>4)*8 + j.
// C/D: col(expert) = lane&15, row(token) = (lane>>4)*4 + reg.
// ---------------------------------------------------------------------------
__global__ __launch_bounds__(256) void router_gemm(const float* __restrict__ X,
                                                   const float* __restrict__ W,
                                                   float* __restrict__ logits) {
    __shared__ unsigned short sA[2 * 64 * 8];   // 2 m-subtiles
    __shared__ unsigned short sB[8 * 64 * 8];   // 8 n-subtiles
    const int tid = threadIdx.x;
    const int lane = tid & 63;
    const int wid = tid >> 6;
    const int wm = wid & 1, wn = wid >> 1;
    const int t0 = blockIdx.x * 32;

    // staging assignment
    const int xt = tid >> 3;              // token 0..31
    const int xk = (tid & 7) * 4;         // k within tile, {0,4,..,28}
    const int we = tid >> 1;              // expert 0..127
    const int wk0 = (tid & 1) * 16;       // k base {0,16}

    const float* Xp = X + (size_t)(t0 + xt) * HIDDEN + xk;
    const float* Wp = W + (size_t)we * HIDDEN + wk0;

    const int aIdx = (((xt >> 4) * 64 + (xk >> 3) * 16 + (xt & 15)) * 8) + (xk & 7);
    int bIdx[4];
#pragma unroll
    for (int i = 0; i < 4; ++i) {
        const int kk4 = wk0 + i * 4;
        bIdx[i] = (((we >> 4) * 64 + (kk4 >> 3) * 16 + (we & 15)) * 8) + (kk4 & 7);
    }

    f32x4 acc[4];
#pragma unroll
    for (int nt = 0; nt < 4; ++nt) acc[nt] = (f32x4){0.f, 0.f, 0.f, 0.f};

    // prefetch kt=0
    float4 px = *(const float4*)(Xp);
    float4 pw[4];
#pragma unroll
    for (int i = 0; i < 4; ++i) pw[i] = *(const float4*)(Wp + i * 4);

    for (int kt = 0; kt < HIDDEN; kt += 32) {
        __syncthreads();   // prior compute finished reading LDS
        {
            ushort4 v;
            v.x = f2bf(px.x); v.y = f2bf(px.y); v.z = f2bf(px.z); v.w = f2bf(px.w);
            *(ushort4*)&sA[aIdx] = v;
        }
#pragma unroll
        for (int i = 0; i < 4; ++i) {
            ushort4 v;
            v.x = f2bf(pw[i].x); v.y = f2bf(pw[i].y);
            v.z = f2bf(pw[i].z); v.w = f2bf(pw[i].w);
            *(ushort4*)&sB[bIdx[i]] = v;
        }
        __syncthreads();

        if (kt + 32 < HIDDEN) {   // prefetch next tile; overlaps MFMA below
            px = *(const float4*)(Xp + kt + 32);
#pragma unroll
            for (int i = 0; i < 4; ++i) pw[i] = *(const float4*)(Wp + kt + 32 + i * 4);
        }

        const bf16x8 a = *(const bf16x8*)&sA[(wm * 64 + lane) * 8];
#pragma unroll
        for (int nt = 0; nt < 4; ++nt) {
            const bf16x8 b = *(const bf16x8*)&sB[((wn * 4 + nt) * 64 + lane) * 8];
            acc[nt] = __builtin_amdgcn_mfma_f32_16x16x32_bf16(a, b, acc[nt], 0, 0, 0);
        }
    }

    const int tr = t0 + wm * 16 + (lane >> 4) * 4;   // token row base
    const int ec = wn * 64 + (lane & 15);            // expert col base
#pragma unroll
    for (int nt = 0; nt < 4; ++nt)
#pragma unroll
        for (int r = 0; r < 4; ++r)
            logits[(size_t)(tr + r) * NEXP + ec + nt * 16] = acc[nt][r];
}

// ---------------------------------------------------------------------------
// Kernel 2: top-12 candidates by fp32 logits, exact fp64 recompute of those 12
// dot products (lane = 32-wide K slice), rank top-8 (value desc, index asc),
// renormalized softmax over the top-8. One wave per token.
// ---------------------------------------------------------------------------
__global__ __launch_bounds__(256) void router_topk(const float* __restrict__ logits,
                                                   const float* __restrict__ X,
                                                   const float* __restrict__ W,
                                                   float* __restrict__ top_vals,
                                                   float* __restrict__ top_idx) {
    const int lane = threadIdx.x & 63;
    const int wid = threadIdx.x >> 6;
    const int t = blockIdx.x * 4 + wid;

    // ---- phase A: load fp32 logits (2 per lane)
    const float* lrow = logits + (size_t)t * NEXP;
    const float l0 = lrow[lane];
    const float l1 = lrow[lane + 64];

    // ---- phase B: top-NCAND candidate indices via iterative butterfly argmax
    bool r0 = false, r1 = false;
    int cidx[NCAND];
#pragma unroll
    for (int it = 0; it < NCAND; ++it) {
        const float c0 = r0 ? -FLT_MAX : l0;
        const float c1 = r1 ? -FLT_MAX : l1;
        float v; int id;
        if (c1 > c0) { v = c1; id = lane + 64; }
        else         { v = c0; id = lane; }
#pragma unroll
        for (int off = 1; off < 64; off <<= 1) {
            const float ov = __shfl_xor(v, off);
            const int   oi = __shfl_xor(id, off);
            if (ov > v || (ov == v && oi < id)) { v = ov; id = oi; }
        }
        cidx[it] = id;           // uniform across wave
        if (id == lane) r0 = true;
        else if (id == lane + 64) r1 = true;
    }

    // ---- phase C: exact fp64 dot for each candidate. lane owns k slice of 32.
    const float* xrow = X + (size_t)t * HIDDEN + lane * 32;
    double xd[32];
#pragma unroll
    for (int i = 0; i < 8; ++i) {
        const float4 v = *(const float4*)(xrow + i * 4);
        xd[i * 4 + 0] = (double)v.x; xd[i * 4 + 1] = (double)v.y;
        xd[i * 4 + 2] = (double)v.z; xd[i * 4 + 3] = (double)v.w;
    }
    double acc[NCAND];
#pragma unroll
    for (int c = 0; c < NCAND; ++c) {
        const float* wrow = W + (size_t)cidx[c] * HIDDEN + lane * 32;
        double a0 = 0.0, a1 = 0.0;
#pragma unroll
        for (int i = 0; i < 8; ++i) {
            const float4 w = *(const float4*)(wrow + i * 4);
            a0 = fma((double)w.x, xd[i * 4 + 0], a0);
            a1 = fma((double)w.y, xd[i * 4 + 1], a1);
            a0 = fma((double)w.z, xd[i * 4 + 2], a0);
            a1 = fma((double)w.w, xd[i * 4 + 3], a1);
        }
        acc[c] = a0 + a1;
    }
    // ---- phase D: butterfly reduce each candidate across 64 lanes
#pragma unroll
    for (int c = 0; c < NCAND; ++c)
#pragma unroll
        for (int off = 1; off < 64; off <<= 1)
            acc[c] += __shfl_xor(acc[c], off);

    // ---- phase E: rank (value desc, index asc), softmax-renorm top-8
    int rank[NCAND];
#pragma unroll
    for (int c = 0; c < NCAND; ++c) {
        int r = 0;
#pragma unroll
        for (int m = 0; m < NCAND; ++m)
            if (acc[m] > acc[c] || (acc[m] == acc[c] && cidx[m] < cidx[c])) ++r;
        rank[c] = r;
    }
    double vmax = acc[0];
#pragma unroll
    for (int c = 0; c < NCAND; ++c) if (rank[c] == 0) vmax = acc[c];
    float ex[NCAND]; float s = 0.f;
#pragma unroll
    for (int c = 0; c < NCAND; ++c) {
        ex[c] = (rank[c] < TOPK) ? expf((float)(acc[c] - vmax)) : 0.f;
        s += ex[c];
    }
    const float inv = 1.f / s;
    if (lane == 0) {
#pragma unroll
        for (int c = 0; c < NCAND; ++c) {
            if (rank[c] < TOPK) {
                top_vals[(size_t)t * TOPK + rank[c]] = ex[c] * inv;
                top_idx[(size_t)t * TOPK + rank[c]] = (float)cidx[c];
            }
        }
    }
}

extern "C" void kernel_launch(void* const* d_in, const int* in_sizes, int n_in,
                              void* d_out, int out_size, void* d_ws, size_t ws_size,
                              hipStream_t stream) {
    const float* X = (const float*)d_in[0];   // [16384, 2048] f32
    const float* W = (const float*)d_in[1];   // [128, 2048] f32
    float* logits = (float*)d_out;                          // [16384,128]
    float* tvals  = logits + (size_t)TOKENS * NEXP;         // [16384,8]
    float* tidx   = tvals + (size_t)TOKENS * TOPK;          // [16384,8]

    router_gemm<<<TOKENS / 32, 256, 0, stream>>>(X, W, logits);
    router_topk<<<TOKENS / 4, 256, 0, stream>>>(logits, X, W, tvals, tidx);
}

// Round 3
// 294.241 us; speedup vs baseline: 2.3339x; 2.3339x over previous
//
#include <hip/hip_runtime.h>
#include <float.h>
#include <math.h>

#define TOKENS 16384
#define HIDDEN 2048
#define NEXP 128
#define TOPK 8
#define NCAND 12
#define DELTA 1e-3f

#define BM 64
#define BN 64
#define BK 64

typedef float f32x4 __attribute__((ext_vector_type(4)));
typedef short bf16x8 __attribute__((ext_vector_type(8)));

// truncating fp32 -> bf16 split helpers (exact residual: r = a - trunc_bf16(a))
__device__ __forceinline__ unsigned pack_hi(float a, float b) {
    return (__float_as_uint(a) >> 16) | (__float_as_uint(b) & 0xFFFF0000u);
}
__device__ __forceinline__ float resid(float a) {
    return a - __uint_as_float(__float_as_uint(a) & 0xFFFF0000u);
}

// LDS index (in ushorts): [mtile(4)][kchunk(2)][hi/lo(2)][lane(64)][8]
__device__ __forceinline__ int ldsIdx(int mt, int kc, int hl, int lane) {
    return (((mt * 2 + kc) * 2 + hl) * 64 + lane) * 8;
}

// ---------------------------------------------------------------------------
// K1: split-bf16 MFMA GEMM. logits[t][e] = sum_k X[t][k]*W[e][k]
// x = xh + xl, w = wh + wl (bf16 each); logit ~= xh.wh + xh.wl + xl.wh
// (dropped xl.wl <= 2^-16 relative per product -> |err| ~1e-5 rms).
// Grid 512: bx>>1 -> 64-token tile, bx&1 -> 64-expert tile. 256 thr, 4 waves:
// wave (wm=wid&1, wn=wid>>1) computes 32 tok x 32 exp = 2x2 MFMA tiles.
// ---------------------------------------------------------------------------
__global__ __launch_bounds__(256) void router_gemm(const float* __restrict__ X,
                                                   const float* __restrict__ W,
                                                   float* __restrict__ logits) {
    __shared__ unsigned short sA[4 * 2 * 2 * 64 * 8];   // 16 KB
    __shared__ unsigned short sB[4 * 2 * 2 * 64 * 8];   // 16 KB

    const int tid = threadIdx.x;
    const int lane = tid & 63;
    const int wid = tid >> 6;
    const int wm = wid & 1, wn = wid >> 1;
    const int t0 = (blockIdx.x >> 1) * BM;
    const int e0 = (blockIdx.x & 1) * BN;

    // staging map: thread owns 16 consecutive k of one row
    const int xt = tid >> 2;          // row 0..63 (token / expert)
    const int xq = tid & 3;           // k quarter: k base = xq*16
    const int kc0 = xq >> 1;          // k-chunk (0/1)
    const int g0 = (xq * 2) & 3;      // 8-el group within chunk {0,2}
    const int m15 = xt & 15;
    const int mtile = xt >> 4;
    const int offH0 = ldsIdx(mtile, kc0, 0, g0 * 16 + m15);
    const int offH1 = ldsIdx(mtile, kc0, 0, (g0 + 1) * 16 + m15);
    const int offL0 = ldsIdx(mtile, kc0, 1, g0 * 16 + m15);
    const int offL1 = ldsIdx(mtile, kc0, 1, (g0 + 1) * 16 + m15);

    const float* Xp = X + (size_t)(t0 + xt) * HIDDEN + xq * 16;
    const float* Wp = W + (size_t)(e0 + xt) * HIDDEN + xq * 16;

    f32x4 acc[2][2];
#pragma unroll
    for (int i = 0; i < 2; ++i)
#pragma unroll
        for (int j = 0; j < 2; ++j) acc[i][j] = (f32x4){0.f, 0.f, 0.f, 0.f};

    float4 px[4], pw[4];
#pragma unroll
    for (int i = 0; i < 4; ++i) {
        px[i] = *(const float4*)(Xp + i * 4);
        pw[i] = *(const float4*)(Wp + i * 4);
    }

#pragma unroll 1
    for (int kt = 0; kt < HIDDEN; kt += BK) {
        __syncthreads();   // previous iter's LDS reads done
        // ---- convert + stage (8-el unit = uint4 of packed bf16 pairs)
        {
            uint4 h, l;
            h.x = pack_hi(px[0].x, px[0].y); h.y = pack_hi(px[0].z, px[0].w);
            h.z = pack_hi(px[1].x, px[1].y); h.w = pack_hi(px[1].z, px[1].w);
            l.x = pack_hi(resid(px[0].x), resid(px[0].y));
            l.y = pack_hi(resid(px[0].z), resid(px[0].w));
            l.z = pack_hi(resid(px[1].x), resid(px[1].y));
            l.w = pack_hi(resid(px[1].z), resid(px[1].w));
            *(uint4*)&sA[offH0] = h; *(uint4*)&sA[offL0] = l;
            h.x = pack_hi(px[2].x, px[2].y); h.y = pack_hi(px[2].z, px[2].w);
            h.z = pack_hi(px[3].x, px[3].y); h.w = pack_hi(px[3].z, px[3].w);
            l.x = pack_hi(resid(px[2].x), resid(px[2].y));
            l.y = pack_hi(resid(px[2].z), resid(px[2].w));
            l.z = pack_hi(resid(px[3].x), resid(px[3].y));
            l.w = pack_hi(resid(px[3].z), resid(px[3].w));
            *(uint4*)&sA[offH1] = h; *(uint4*)&sA[offL1] = l;

            h.x = pack_hi(pw[0].x, pw[0].y); h.y = pack_hi(pw[0].z, pw[0].w);
            h.z = pack_hi(pw[1].x, pw[1].y); h.w = pack_hi(pw[1].z, pw[1].w);
            l.x = pack_hi(resid(pw[0].x), resid(pw[0].y));
            l.y = pack_hi(resid(pw[0].z), resid(pw[0].w));
            l.z = pack_hi(resid(pw[1].x), resid(pw[1].y));
            l.w = pack_hi(resid(pw[1].z), resid(pw[1].w));
            *(uint4*)&sB[offH0] = h; *(uint4*)&sB[offL0] = l;
            h.x = pack_hi(pw[2].x, pw[2].y); h.y = pack_hi(pw[2].z, pw[2].w);
            h.z = pack_hi(pw[3].x, pw[3].y); h.w = pack_hi(pw[3].z, pw[3].w);
            l.x = pack_hi(resid(pw[2].x), resid(pw[2].y));
            l.y = pack_hi(resid(pw[2].z), resid(pw[2].w));
            l.z = pack_hi(resid(pw[3].x), resid(pw[3].y));
            l.w = pack_hi(resid(pw[3].z), resid(pw[3].w));
            *(uint4*)&sB[offH1] = h; *(uint4*)&sB[offL1] = l;
        }
        __syncthreads();

        if (kt + BK < HIDDEN) {   // prefetch next tile (overlaps MFMA)
#pragma unroll
            for (int i = 0; i < 4; ++i) {
                px[i] = *(const float4*)(Xp + kt + BK + i * 4);
                pw[i] = *(const float4*)(Wp + kt + BK + i * 4);
            }
        }

#pragma unroll
        for (int kc = 0; kc < 2; ++kc) {
            bf16x8 ah[2], al[2], bh[2], bl[2];
#pragma unroll
            for (int mt = 0; mt < 2; ++mt) {
                ah[mt] = *(const bf16x8*)&sA[ldsIdx(wm * 2 + mt, kc, 0, lane)];
                al[mt] = *(const bf16x8*)&sA[ldsIdx(wm * 2 + mt, kc, 1, lane)];
            }
#pragma unroll
            for (int nt = 0; nt < 2; ++nt) {
                bh[nt] = *(const bf16x8*)&sB[ldsIdx(wn * 2 + nt, kc, 0, lane)];
                bl[nt] = *(const bf16x8*)&sB[ldsIdx(wn * 2 + nt, kc, 1, lane)];
            }
#pragma unroll
            for (int mt = 0; mt < 2; ++mt)
#pragma unroll
                for (int nt = 0; nt < 2; ++nt) {
                    acc[mt][nt] = __builtin_amdgcn_mfma_f32_16x16x32_bf16(ah[mt], bh[nt], acc[mt][nt], 0, 0, 0);
                    acc[mt][nt] = __builtin_amdgcn_mfma_f32_16x16x32_bf16(ah[mt], bl[nt], acc[mt][nt], 0, 0, 0);
                    acc[mt][nt] = __builtin_amdgcn_mfma_f32_16x16x32_bf16(al[mt], bh[nt], acc[mt][nt], 0, 0, 0);
                }
        }
    }

    // epilogue: C/D layout col=lane&15 (expert), row=(lane>>4)*4+r (token)
#pragma unroll
    for (int mt = 0; mt < 2; ++mt) {
        const int tr = t0 + wm * 32 + mt * 16 + (lane >> 4) * 4;
#pragma unroll
        for (int nt = 0; nt < 2; ++nt) {
            const int ec = e0 + wn * 32 + nt * 16 + (lane & 15);
#pragma unroll
            for (int r = 0; r < 4; ++r)
                logits[(size_t)(tr + r) * NEXP + ec] = acc[mt][nt][r];
        }
    }
}

// ---------------------------------------------------------------------------
// top-NCAND argmax selection (iterative butterfly, jax tie-break: lower index
// wins on equal value). All lanes end with identical vals/idxs.
// ---------------------------------------------------------------------------
__device__ __forceinline__ void top_cand(const float* __restrict__ lrow, int lane,
                                         float* vals, int* idxs) {
    const float l0 = lrow[lane];
    const float l1 = lrow[lane + 64];
    bool r0 = false, r1 = false;
#pragma unroll
    for (int it = 0; it < NCAND; ++it) {
        const float c0 = r0 ? -FLT_MAX : l0;
        const float c1 = r1 ? -FLT_MAX : l1;
        float v; int id;
        if (c1 > c0) { v = c1; id = lane + 64; }
        else         { v = c0; id = lane; }
#pragma unroll
        for (int off = 1; off < 64; off <<= 1) {
            const float ov = __shfl_xor(v, off);
            const int   oi = __shfl_xor(id, off);
            if (ov > v || (ov == v && oi < id)) { v = ov; id = oi; }
        }
        vals[it] = v; idxs[it] = id;
        if (id == lane) r0 = true;
        else if (id == lane + 64) r1 = true;
    }
}

// ---------------------------------------------------------------------------
// K2: per-token select. Clean tokens (all adjacent gaps among ranks 0..8
// >= DELTA) -> write outputs from approx logits. Ambiguous -> push to list.
// ---------------------------------------------------------------------------
__global__ __launch_bounds__(256) void router_select(const float* __restrict__ logits,
                                                     float* __restrict__ top_vals,
                                                     float* __restrict__ top_idx,
                                                     int* __restrict__ cnt,
                                                     int* __restrict__ list) {
    const int lane = threadIdx.x & 63;
    const int wid = threadIdx.x >> 6;
    const int t = blockIdx.x * 4 + wid;

    float vals[NCAND]; int idxs[NCAND];
    top_cand(logits + (size_t)t * NEXP, lane, vals, idxs);

    float ming = FLT_MAX;
#pragma unroll
    for (int i = 0; i < TOPK; ++i) ming = fminf(ming, vals[i] - vals[i + 1]);

    if (ming < DELTA) {
        if (lane == 0) { const int p = atomicAdd(cnt, 1); list[p] = t; }
    } else if (lane == 0) {
        const float m = vals[0];
        float e[TOPK], s = 0.f;
#pragma unroll
        for (int i = 0; i < TOPK; ++i) { e[i] = expf(vals[i] - m); s += e[i]; }
        const float inv = 1.f / s;
#pragma unroll
        for (int i = 0; i < TOPK; ++i) {
            top_vals[(size_t)t * TOPK + i] = e[i] * inv;
            top_idx[(size_t)t * TOPK + i] = (float)idxs[i];
        }
    }
}

// ---------------------------------------------------------------------------
// K3: exact fp64 refine of flagged tokens. One wave per flagged token,
// grid-stride over the list. Coalesced: lane i reads 16B at (k = j*256+lane*4).
// ---------------------------------------------------------------------------
__global__ __launch_bounds__(256) void router_refine(const float* __restrict__ logits,
                                                     const float* __restrict__ X,
                                                     const float* __restrict__ W,
                                                     float* __restrict__ top_vals,
                                                     float* __restrict__ top_idx,
                                                     const int* __restrict__ cnt,
                                                     const int* __restrict__ list) {
    const int lane = threadIdx.x & 63;
    const int gw = blockIdx.x * 4 + (threadIdx.x >> 6);
    const int nwaves = gridDim.x * 4;
    const int n = *cnt;

    for (int ii = gw; ii < n; ii += nwaves) {
        const int t = list[ii];
        float vals[NCAND]; int idxs[NCAND];
        top_cand(logits + (size_t)t * NEXP, lane, vals, idxs);

        // exact fp64 recompute of the NCAND candidate logits
        const float* xr = X + (size_t)t * HIDDEN;
        double xd[32];
#pragma unroll
        for (int j = 0; j < 8; ++j) {
            const float4 v = *(const float4*)(xr + j * 256 + lane * 4);
            xd[j * 4 + 0] = (double)v.x; xd[j * 4 + 1] = (double)v.y;
            xd[j * 4 + 2] = (double)v.z; xd[j * 4 + 3] = (double)v.w;
        }
        double acc[NCAND];
#pragma unroll
        for (int c = 0; c < NCAND; ++c) {
            const float* wr = W + (size_t)idxs[c] * HIDDEN;
            double a0 = 0.0, a1 = 0.0;
#pragma unroll
            for (int j = 0; j < 8; ++j) {
                const float4 w = *(const float4*)(wr + j * 256 + lane * 4);
                a0 = fma((double)w.x, xd[j * 4 + 0], a0);
                a1 = fma((double)w.y, xd[j * 4 + 1], a1);
                a0 = fma((double)w.z, xd[j * 4 + 2], a0);
                a1 = fma((double)w.w, xd[j * 4 + 3], a1);
            }
            acc[c] = a0 + a1;
        }
#pragma unroll
        for (int c = 0; c < NCAND; ++c)
#pragma unroll
            for (int off = 1; off < 64; off <<= 1)
                acc[c] += __shfl_xor(acc[c], off);

        // rank (value desc, index asc)
        int rank[NCAND];
#pragma unroll
        for (int c = 0; c < NCAND; ++c) {
            int r = 0;
#pragma unroll
            for (int m = 0; m < NCAND; ++m)
                if (acc[m] > acc[c] || (acc[m] == acc[c] && idxs[m] < idxs[c])) ++r;
            rank[c] = r;
        }
        double vmax = acc[0];
#pragma unroll
        for (int c = 0; c < NCAND; ++c) if (rank[c] == 0) vmax = acc[c];
        float e[NCAND], s = 0.f;
#pragma unroll
        for (int c = 0; c < NCAND; ++c) {
            e[c] = (rank[c] < TOPK) ? expf((float)(acc[c] - vmax)) : 0.f;
            s += e[c];
        }
        const float inv = 1.f / s;
        if (lane == 0) {
#pragma unroll
            for (int c = 0; c < NCAND; ++c)
                if (rank[c] < TOPK) {
                    top_vals[(size_t)t * TOPK + rank[c]] = e[c] * inv;
                    top_idx[(size_t)t * TOPK + rank[c]] = (float)idxs[c];
                }
        }
    }
}

extern "C" void kernel_launch(void* const* d_in, const int* in_sizes, int n_in,
                              void* d_out, int out_size, void* d_ws, size_t ws_size,
                              hipStream_t stream) {
    const float* X = (const float*)d_in[0];   // [16384, 2048] f32
    const float* W = (const float*)d_in[1];   // [128, 2048] f32
    float* logits = (float*)d_out;                          // [16384,128]
    float* tvals  = logits + (size_t)TOKENS * NEXP;         // [16384,8]
    float* tidx   = tvals + (size_t)TOKENS * TOPK;          // [16384,8]
    int* cnt  = (int*)d_ws;
    int* list = (int*)d_ws + 16;

    hipMemsetAsync(d_ws, 0, 64, stream);
    router_gemm<<<(TOKENS / BM) * (NEXP / BN), 256, 0, stream>>>(X, W, logits);
    router_select<<<TOKENS / 4, 256, 0, stream>>>(logits, tvals, tidx, cnt, list);
    router_refine<<<256, 256, 0, stream>>>(logits, X, W, tvals, tidx, cnt, list);
}